// Round 1
// baseline (24152.029 us; speedup 1.0000x reference)
//
#include <hip/hip_runtime.h>
#include <cstdint>

// Problem constants
#define V 20000
#define E 256
#define H 512
#define D_IN 3
#define B 64
#define T_SRC 200
#define T_TRG 128

// Output layout: eid_result [128][64][20000] then rate_result [128][64]
#define OUT_EID_ELEMS (128LL * 64 * 20000)   // 163,840,000
#define ROW_ELEMS (64 * 20000)               // 1,280,000

__device__ __forceinline__ float sigmoidf_(float x) {
    return 1.f / (1.f + expf(-x));
}

// ---------------------------------------------------------------------------
// Zero-init: out row 0 (eid + rate) and hT0
// f4 counts: out row0 = 320000, hT0 = 8192, rate row0 = 16  -> 328208 total
__global__ __launch_bounds__(256)
void k_zero(float* __restrict__ out, float* __restrict__ hT0) {
    int id = blockIdx.x * 256 + threadIdx.x;
    float4 z; z.x = 0.f; z.y = 0.f; z.z = 0.f; z.w = 0.f;
    if (id < 320000) {
        ((float4*)out)[id] = z;
    } else if (id < 320000 + 8192) {
        ((float4*)hT0)[id - 320000] = z;
    } else if (id < 320000 + 8192 + 16) {
        ((float4*)(out + OUT_EID_ELEMS))[id - (320000 + 8192)] = z;
    }
}

// ---------------------------------------------------------------------------
// Build xT for decoder step 0 from trg_eid[0], trg_rate[0].
// xT layout: [257 k][64 b]
__global__ __launch_bounds__(256)
void k_build_x0(const float* __restrict__ emb, const int* __restrict__ trg_eid,
                const float* __restrict__ trg_rate, float* __restrict__ xT) {
    int id = blockIdx.x * 256 + threadIdx.x;
    if (id >= 257 * 64) return;
    int k = id >> 6, b = id & 63;
    if (k < 256) {
        int e = trg_eid[b];                 // row 0
        xT[k * 64 + b] = emb[e * 256 + k];
    } else {
        xT[256 * 64 + b] = trg_rate[b];     // row 0
    }
}

// ---------------------------------------------------------------------------
// Encoder GRU step. Grid = 512 blocks (one per jH), 256 threads = 4 waves
// splitting K=512 into quarters. lane = b. hT layout [k][b].
__global__ __launch_bounds__(256)
void k_enc_gru(const float* __restrict__ src_t, const int* __restrict__ src_len,
               const float* __restrict__ Wih, const float* __restrict__ Whh,
               const float* __restrict__ bih, const float* __restrict__ bhh,
               const float* __restrict__ hin, float* __restrict__ hout, int t) {
    const int tid = threadIdx.x;
    const int lane = tid & 63;
    const int w = tid >> 6;          // k-quarter 0..3
    const int jH = blockIdx.x;       // 0..511
    const float* wr = Whh + (size_t)jH * 512;
    const float* wz = Whh + (size_t)(512 + jH) * 512;
    const float* wn = Whh + (size_t)(1024 + jH) * 512;
    float pr = 0.f, pz = 0.f, pn = 0.f;
    const int k0 = w * 128;
#pragma unroll 8
    for (int k = k0; k < k0 + 128; ++k) {
        float hv = hin[k * 64 + lane];
        pr = fmaf(hv, wr[k], pr);
        pz = fmaf(hv, wz[k], pz);
        pn = fmaf(hv, wn[k], pn);
    }
    __shared__ float hp[4][3][64];
    hp[w][0][lane] = pr; hp[w][1][lane] = pz; hp[w][2][lane] = pn;
    __syncthreads();
    if (w == 0) {
        // gi = x @ Wih.T + bih  (K = 3)
        float x0 = src_t[lane * 3 + 0];
        float x1 = src_t[lane * 3 + 1];
        float x2 = src_t[lane * 3 + 2];
        float gr = bih[jH]        + x0 * Wih[jH * 3]            + x1 * Wih[jH * 3 + 1]            + x2 * Wih[jH * 3 + 2];
        float gz = bih[512 + jH]  + x0 * Wih[(512 + jH) * 3]    + x1 * Wih[(512 + jH) * 3 + 1]    + x2 * Wih[(512 + jH) * 3 + 2];
        float gn = bih[1024 + jH] + x0 * Wih[(1024 + jH) * 3]   + x1 * Wih[(1024 + jH) * 3 + 1]   + x2 * Wih[(1024 + jH) * 3 + 2];
        float hr = hp[0][0][lane] + hp[1][0][lane] + hp[2][0][lane] + hp[3][0][lane] + bhh[jH];
        float hz = hp[0][1][lane] + hp[1][1][lane] + hp[2][1][lane] + hp[3][1][lane] + bhh[512 + jH];
        float hn = hp[0][2][lane] + hp[1][2][lane] + hp[2][2][lane] + hp[3][2][lane] + bhh[1024 + jH];
        float r = sigmoidf_(gr + hr);
        float z = sigmoidf_(gz + hz);
        float n = tanhf(gn + r * hn);
        float hprev = hin[jH * 64 + lane];
        float hnew = (1.f - z) * n + z * hprev;
        hout[jH * 64 + lane] = (t < src_len[lane]) ? hnew : hprev;
    }
}

// ---------------------------------------------------------------------------
// Decoder GRU step. Same structure; x from xT [257][64].
__global__ __launch_bounds__(256)
void k_dec_gru(const float* __restrict__ xT,
               const float* __restrict__ Wih, const float* __restrict__ Whh,
               const float* __restrict__ bih, const float* __restrict__ bhh,
               const float* __restrict__ hin, float* __restrict__ hout) {
    const int tid = threadIdx.x;
    const int lane = tid & 63;
    const int w = tid >> 6;
    const int jH = blockIdx.x;
    const float* wr = Whh + (size_t)jH * 512;
    const float* wz = Whh + (size_t)(512 + jH) * 512;
    const float* wn = Whh + (size_t)(1024 + jH) * 512;
    float pr = 0.f, pz = 0.f, pn = 0.f;
    const int k0 = w * 128;
#pragma unroll 8
    for (int k = k0; k < k0 + 128; ++k) {
        float hv = hin[k * 64 + lane];
        pr = fmaf(hv, wr[k], pr);
        pz = fmaf(hv, wz[k], pz);
        pn = fmaf(hv, wn[k], pn);
    }
    __shared__ float hp[4][3][64];
    hp[w][0][lane] = pr; hp[w][1][lane] = pz; hp[w][2][lane] = pn;
    __syncthreads();
    if (w == 0) {
        const float* ir = Wih + (size_t)jH * 257;
        const float* iz = Wih + (size_t)(512 + jH) * 257;
        const float* in_ = Wih + (size_t)(1024 + jH) * 257;
        float gr = bih[jH], gz = bih[512 + jH], gn = bih[1024 + jH];
#pragma unroll 4
        for (int k = 0; k < 257; ++k) {
            float xv = xT[k * 64 + lane];
            gr = fmaf(xv, ir[k], gr);
            gz = fmaf(xv, iz[k], gz);
            gn = fmaf(xv, in_[k], gn);
        }
        float hr = hp[0][0][lane] + hp[1][0][lane] + hp[2][0][lane] + hp[3][0][lane] + bhh[jH];
        float hz = hp[0][1][lane] + hp[1][1][lane] + hp[2][1][lane] + hp[3][1][lane] + bhh[512 + jH];
        float hn = hp[0][2][lane] + hp[1][2][lane] + hp[2][2][lane] + hp[3][2][lane] + bhh[1024 + jH];
        float r = sigmoidf_(gr + hr);
        float z = sigmoidf_(gz + hz);
        float n = tanhf(gn + r * hn);
        float hprev = hin[jH * 64 + lane];
        hout[jH * 64 + lane] = (1.f - z) * n + z * hprev;
    }
}

// ---------------------------------------------------------------------------
// Logits: out_row[b][v] = sum_k hT[k][b]*peW[v][k] + peb[v]
// Tile 64v x 64b, K staged in chunks of 64. 313 blocks.
__global__ __launch_bounds__(256)
void k_logits(const float* __restrict__ hT, const float* __restrict__ peW,
              const float* __restrict__ peb, float* __restrict__ outrow) {
    __shared__ float hs[64 * 68];   // [k][b], pad 68
    __shared__ float ps[64 * 68];   // [k][v], pad 68
    const int tid = threadIdx.x;
    const int v0 = blockIdx.x * 64;
    const int vq = tid & 15;        // 16 vq * 4 = 64 v
    const int bq = tid >> 4;        // 16 bq * 4 = 64 b
    float acc[4][4];
#pragma unroll
    for (int i = 0; i < 4; ++i)
#pragma unroll
        for (int j = 0; j < 4; ++j) acc[i][j] = 0.f;

    for (int kc = 0; kc < 512; kc += 64) {
        __syncthreads();
        // stage h chunk: natural [k][b] copy, coalesced + conflict-free
#pragma unroll
        for (int i = 0; i < 16; ++i) {
            int id = tid + i * 256;
            int kr = id >> 6, b = id & 63;
            hs[kr * 68 + b] = hT[(kc + kr) * 64 + b];
        }
        // stage pe chunk transposed: read rows coalesced, write [k][v]
#pragma unroll
        for (int i = 0; i < 16; ++i) {
            int id = tid + i * 256;
            int vr = id >> 6, kk = id & 63;
            int v = v0 + vr;
            ps[kk * 68 + vr] = (v < V) ? peW[(size_t)v * 512 + kc + kk] : 0.f;
        }
        __syncthreads();
#pragma unroll 4
        for (int kk = 0; kk < 64; ++kk) {
            float4 hv = *(const float4*)&hs[kk * 68 + bq * 4];
            float4 pv = *(const float4*)&ps[kk * 68 + vq * 4];
            acc[0][0] = fmaf(hv.x, pv.x, acc[0][0]);
            acc[0][1] = fmaf(hv.x, pv.y, acc[0][1]);
            acc[0][2] = fmaf(hv.x, pv.z, acc[0][2]);
            acc[0][3] = fmaf(hv.x, pv.w, acc[0][3]);
            acc[1][0] = fmaf(hv.y, pv.x, acc[1][0]);
            acc[1][1] = fmaf(hv.y, pv.y, acc[1][1]);
            acc[1][2] = fmaf(hv.y, pv.z, acc[1][2]);
            acc[1][3] = fmaf(hv.y, pv.w, acc[1][3]);
            acc[2][0] = fmaf(hv.z, pv.x, acc[2][0]);
            acc[2][1] = fmaf(hv.z, pv.y, acc[2][1]);
            acc[2][2] = fmaf(hv.z, pv.z, acc[2][2]);
            acc[2][3] = fmaf(hv.z, pv.w, acc[2][3]);
            acc[3][0] = fmaf(hv.w, pv.x, acc[3][0]);
            acc[3][1] = fmaf(hv.w, pv.y, acc[3][1]);
            acc[3][2] = fmaf(hv.w, pv.z, acc[3][2]);
            acc[3][3] = fmaf(hv.w, pv.w, acc[3][3]);
        }
    }
    int v = v0 + vq * 4;
    if (v < V) {
        float4 pb = *(const float4*)&peb[v];
#pragma unroll
        for (int bi = 0; bi < 4; ++bi) {
            int b = bq * 4 + bi;
            float4 o;
            o.x = acc[bi][0] + pb.x;
            o.y = acc[bi][1] + pb.y;
            o.z = acc[bi][2] + pb.z;
            o.w = acc[bi][3] + pb.w;
            *(float4*)&outrow[(size_t)b * V + v] = o;
        }
    }
}

// ---------------------------------------------------------------------------
// Per-b reduce over V: max + first-index argmax, then sum exp.
// Writes c_all[s*64+b] = m + log(sum), idxb[b] = argmax. 64 blocks.
__global__ __launch_bounds__(256)
void k_reduce(const float* __restrict__ row, float* __restrict__ c_all,
              int* __restrict__ idxb, int s) {
    const int b = blockIdx.x;
    const int tid = threadIdx.x;
    const float4* p4 = (const float4*)(row + (size_t)b * V);
    float m = -1e30f; int mi = 0;
    for (int i = tid; i < V / 4; i += 256) {
        float4 x = p4[i];
        int v = i * 4;
        if (x.x > m) { m = x.x; mi = v; }
        if (x.y > m) { m = x.y; mi = v + 1; }
        if (x.z > m) { m = x.z; mi = v + 2; }
        if (x.w > m) { m = x.w; mi = v + 3; }
    }
    __shared__ float sm[256];
    __shared__ int si[256];
    sm[tid] = m; si[tid] = mi;
    __syncthreads();
    for (int off = 128; off > 0; off >>= 1) {
        if (tid < off) {
            float om = sm[tid + off]; int oi = si[tid + off];
            if (om > sm[tid] || (om == sm[tid] && oi < si[tid])) { sm[tid] = om; si[tid] = oi; }
        }
        __syncthreads();
    }
    float gm = sm[0];
    int gidx = si[0];
    __syncthreads();
    float acc = 0.f;
    for (int i = tid; i < V / 4; i += 256) {
        float4 x = p4[i];
        acc += expf(x.x - gm) + expf(x.y - gm) + expf(x.z - gm) + expf(x.w - gm);
    }
    sm[tid] = acc;
    __syncthreads();
    for (int off = 128; off > 0; off >>= 1) {
        if (tid < off) sm[tid] += sm[tid + off];
        __syncthreads();
    }
    if (tid == 0) {
        c_all[s * 64 + b] = gm + logf(sm[0]);
        idxb[b] = gidx;
    }
}

// ---------------------------------------------------------------------------
// Rate head: r1 = relu(cat(emb[idx], h) @ r1W.T + r1b); rate = sigmoid(r1.r2W + r2b)
// Also builds next-step xT (emb row + rate). 64 blocks (one per b).
__global__ __launch_bounds__(256)
void k_rate(const float* __restrict__ emb, const float* __restrict__ hT,
            const float* __restrict__ r1W, const float* __restrict__ r1b,
            const float* __restrict__ r2W, const float* __restrict__ r2b,
            const int* __restrict__ idxb, float* __restrict__ out_rate,
            float* __restrict__ xT) {
    const int b = blockIdx.x;
    const int tid = threadIdx.x;
    __shared__ float xc[768];
    const int e = idxb[b];
    for (int k = tid; k < 768; k += 256)
        xc[k] = (k < 256) ? emb[e * 256 + k] : hT[(k - 256) * 64 + b];
    __syncthreads();
    __shared__ float r1s[512];
    for (int j = tid; j < 512; j += 256) {
        const float4* wrow = (const float4*)(r1W + (size_t)j * 768);
        const float4* x4 = (const float4*)xc;
        float a = r1b[j];
#pragma unroll 4
        for (int k = 0; k < 192; ++k) {
            float4 wv = wrow[k];
            float4 xv = x4[k];
            a = fmaf(xv.x, wv.x, a);
            a = fmaf(xv.y, wv.y, a);
            a = fmaf(xv.z, wv.z, a);
            a = fmaf(xv.w, wv.w, a);
        }
        r1s[j] = fmaxf(a, 0.f);
    }
    __syncthreads();
    float acc = r1s[tid] * r2W[tid] + r1s[tid + 256] * r2W[tid + 256];
    __shared__ float ss[256];
    ss[tid] = acc;
    __syncthreads();
    for (int off = 128; off > 0; off >>= 1) {
        if (tid < off) ss[tid] += ss[tid + off];
        __syncthreads();
    }
    float rate = sigmoidf_(ss[0] + r2b[0]);
    // build next xT and write output rate
    if (tid < 256) xT[tid * 64 + b] = xc[tid];
    if (tid == 0) {
        xT[256 * 64 + b] = rate;
        out_rate[b] = rate;
    }
}

// ---------------------------------------------------------------------------
// Deferred log-softmax finalize: out[t][b][v] -= c_all[(t-1)*64+b], rows 1..127.
// 40,640,000 float4s, grid 158750 x 256 (exact).
__global__ __launch_bounds__(256)
void k_finalize(float* __restrict__ out, const float* __restrict__ c_all) {
    uint32_t id = blockIdx.x * 256 + threadIdx.x;     // f4 index
    uint32_t elem = id * 4;                            // < 162,560,000
    uint32_t t1 = elem / 1280000u;                     // step s = t-1, 0..126
    uint32_t rem = elem - t1 * 1280000u;
    uint32_t b = rem / 20000u;
    float c = c_all[t1 * 64 + b];
    float4* p = (float4*)(out + ROW_ELEMS) + id;
    float4 v = *p;
    v.x -= c; v.y -= c; v.z -= c; v.w -= c;
    *p = v;
}

// ---------------------------------------------------------------------------
extern "C" void kernel_launch(void* const* d_in, const int* in_sizes, int n_in,
                              void* d_out, int out_size, void* d_ws, size_t ws_size,
                              hipStream_t stream) {
    const float* src      = (const float*)d_in[0];
    const int*   src_len  = (const int*)d_in[1];
    const int*   trg_eid  = (const int*)d_in[2];
    const float* trg_rate = (const float*)d_in[3];
    const float* emb      = (const float*)d_in[4];
    const float* enc_Wih  = (const float*)d_in[5];
    const float* enc_Whh  = (const float*)d_in[6];
    const float* enc_bih  = (const float*)d_in[7];
    const float* enc_bhh  = (const float*)d_in[8];
    const float* dec_Wih  = (const float*)d_in[9];
    const float* dec_Whh  = (const float*)d_in[10];
    const float* dec_bih  = (const float*)d_in[11];
    const float* dec_bhh  = (const float*)d_in[12];
    const float* pe_W     = (const float*)d_in[13];
    const float* pe_b     = (const float*)d_in[14];
    const float* r1_W     = (const float*)d_in[15];
    const float* r1_b     = (const float*)d_in[16];
    const float* r2_W     = (const float*)d_in[17];
    const float* r2_b     = (const float*)d_in[18];
    float* out = (float*)d_out;
    float* ws  = (float*)d_ws;

    // workspace layout (floats)
    float* hT0   = ws;                 // 512*64
    float* hT1   = ws + 32768;         // 512*64
    float* xT    = ws + 65536;         // 257*64 = 16448
    float* c_all = ws + 81984;         // 127*64 = 8128
    int*   idxb  = (int*)(ws + 98240); // 64

    float* hT[2] = { hT0, hT1 };

    k_zero<<<1283, 256, 0, stream>>>(out, hT0);

    // Encoder: 200 steps, ping-pong hT. Ends in hT0 (200 even).
    for (int t = 0; t < T_SRC; ++t) {
        k_enc_gru<<<512, 256, 0, stream>>>(src + (size_t)t * B * D_IN, src_len,
                                           enc_Wih, enc_Whh, enc_bih, enc_bhh,
                                           hT[t & 1], hT[1 - (t & 1)], t);
    }

    k_build_x0<<<65, 256, 0, stream>>>(emb, trg_eid, trg_rate, xT);

    // Decoder: 127 steps
    for (int s = 0; s < T_TRG - 1; ++s) {
        const float* hin = hT[s & 1];
        float* hnew = hT[1 - (s & 1)];
        float* row = out + (size_t)(s + 1) * ROW_ELEMS;
        k_dec_gru<<<512, 256, 0, stream>>>(xT, dec_Wih, dec_Whh, dec_bih, dec_bhh,
                                           hin, hnew);
        k_logits<<<313, 256, 0, stream>>>(hnew, pe_W, pe_b, row);
        k_reduce<<<64, 256, 0, stream>>>(row, c_all, idxb, s);
        k_rate<<<64, 256, 0, stream>>>(emb, hnew, r1_W, r1_b, r2_W, r2_b, idxb,
                                       out + OUT_EID_ELEMS + (size_t)(s + 1) * B, xT);
    }

    k_finalize<<<158750, 256, 0, stream>>>(out, c_all);
}